// Round 4
// baseline (611.518 us; speedup 1.0000x reference)
//
#include <hip/hip_runtime.h>
#include <hip/hip_bf16.h>

typedef float f32x4 __attribute__((ext_vector_type(4)));
typedef __bf16 bf16x8 __attribute__((ext_vector_type(8)));
typedef unsigned short ushort_t;
typedef ushort_t u16x8 __attribute__((ext_vector_type(8)));

#define GLDS16(gp, lp)                                                        \
  __builtin_amdgcn_global_load_lds(                                           \
      (__attribute__((address_space(1))) void*)(gp),                          \
      (__attribute__((address_space(3))) void*)(lp), 16, 0, 0)

__device__ __forceinline__ ushort_t f2bf(float f) {
  unsigned u = __float_as_uint(f);
  unsigned r = u + 0x7fffu + ((u >> 16) & 1u);  // round-to-nearest-even
  return (ushort_t)(r >> 16);
}

__device__ __forceinline__ int swz(int row) {
  return (row & 3) ^ ((row >> 2) & 3);
}

// ---------------------------------------------------------------------------
// W1 [K=1024][N=1024] fp32 -> w1t [N][K] bf16 (transpose + convert)
// ---------------------------------------------------------------------------
__global__ __launch_bounds__(256) void prep_w1(const float* __restrict__ w1,
                                               ushort_t* __restrict__ w1t) {
  __shared__ ushort_t tile[64][80];
  const int k0 = blockIdx.x * 64;
  const int n0 = blockIdx.y * 64;
  const int tid = threadIdx.x;
#pragma unroll
  for (int it = 0; it < 16; ++it) {
    int idx = it * 256 + tid;
    int k = idx >> 6, n = idx & 63;
    tile[n][k] = f2bf(w1[(size_t)(k0 + k) * 1024 + n0 + n]);
  }
  __syncthreads();
#pragma unroll
  for (int it = 0; it < 2; ++it) {
    int idx = it * 256 + tid;
    int n = idx >> 3, kk = (idx & 7) * 8;
    bf16x8 v = *(const bf16x8*)&tile[n][kk];
    *(bf16x8*)&w1t[(size_t)(n0 + n) * 1024 + k0 + kk] = v;
  }
}

// ---------------------------------------------------------------------------
// Fused kernel (R2 structure: 512 thr / 8 waves, 2 blocks/CU, tile 128x256,
// BK=32, double-buffered pipelined K-loop, one __syncthreads per kt).
// NEW: prep_x is fused in. Pass nt=0 stages A by loading fp32 x, converting
// to bf16 in registers, ds_write to LDS AND global_store to the xbf
// workspace; passes 1-3 re-read xbf via global_load_lds (L2/L3-hot, same
// block's rows; ordering guaranteed by the per-kt barrier's vmcnt drain).
// ---------------------------------------------------------------------------
#define FOLD_EPILOGUE(ACC)                                                    \
  {                                                                           \
    float bv[4], wv[4];                                                       \
    _Pragma("unroll") for (int ni = 0; ni < 4; ++ni) {                        \
      int col = nt * 256 + wn + ni * 16 + lc;                                 \
      bv[ni] = b1[col];                                                       \
      wv[ni] = w2[col];                                                       \
    }                                                                         \
    _Pragma("unroll") for (int mi = 0; mi < 4; ++mi)                          \
        _Pragma("unroll") for (int r = 0; r < 4; ++r) {                       \
      float s = 0.f;                                                          \
      _Pragma("unroll") for (int ni = 0; ni < 4; ++ni) {                      \
        float h = ACC[mi][ni][r] + bv[ni];                                    \
        h = h > 0.f ? h : 0.f;                                                \
        s += h * wv[ni];                                                      \
      }                                                                       \
      racc[mi][r] += s;                                                       \
    }                                                                         \
  }

template <bool FUSE>
__global__ __launch_bounds__(512, 4) void gemm_fused(
    const float* __restrict__ xsrc, ushort_t* __restrict__ xbf,
    const ushort_t* __restrict__ w1t, const float* __restrict__ b1,
    const float* __restrict__ w2, float* __restrict__ out) {
  __shared__ ushort_t As[2][128 * 32];  // 16 KB
  __shared__ ushort_t Bs[2][256 * 32];  // 32 KB
  __shared__ float lbuf[128];
  __shared__ float abuf[128];  // alpha[j*4+k]

  const int tid = threadIdx.x;
  const int wave = tid >> 6, lane = tid & 63;
  const int quad = lane >> 4, lc = lane & 15;
  const int m0 = blockIdx.x * 128;
  const int wm = (wave & 1) * 64, wn = (wave >> 1) * 64;

  // Staging geometry: A tile 128x32 bf16 = 8 KB = 512 x 16B chunks (1/thread);
  // B tile 256x32 bf16 = 16 KB = 1024 chunks (2/thread). Source column-chunk
  // pre-swizzled so readers' quad^swz(row) lookup lands on the right data.
  const int rA = tid >> 2, cA = (tid & 3) ^ swz(tid >> 2);
  const int rB0 = tid >> 2, cB0 = (tid & 3) ^ swz(rB0);
  const int rB1 = 128 + (tid >> 2), cB1 = (tid & 3) ^ swz(rB1);

  const float* af = xsrc + (size_t)(m0 + rA) * 1024 + cA * 8;  // fp32 source
  ushort_t* axw = nullptr;          // xbf write ptr (pass 0)
  const ushort_t* abf = nullptr;    // xbf read ptr (passes 1-3)
  if constexpr (FUSE) {
    axw = xbf + (size_t)(m0 + rA) * 1024 + cA * 8;
    abf = xbf + (size_t)(m0 + rA) * 1024 + cA * 8;
  }
  const ushort_t* bp0 = w1t + (size_t)rB0 * 1024 + cB0 * 8;
  const ushort_t* bp1 = w1t + (size_t)rB1 * 1024 + cB1 * 8;

  int aoff[4], boff[4];
#pragma unroll
  for (int mi = 0; mi < 4; ++mi) {
    int r = wm + mi * 16 + lc;
    aoff[mi] = r * 32 + (quad ^ swz(r)) * 8;
  }
#pragma unroll
  for (int ni = 0; ni < 4; ++ni) {
    int r = wn + ni * 16 + lc;
    boff[ni] = r * 32 + (quad ^ swz(r)) * 8;
  }

  // Stage tile (nt_, kt_) into buffer `buf`.
  auto stage = [&](int buf, int nt_, int kt_) {
    const size_t cb = (size_t)nt_ * (256 * 1024);
    const int k0 = kt_ * 32;
    GLDS16(bp0 + cb + k0, &Bs[buf][tid * 8]);
    GLDS16(bp1 + cb + k0, &Bs[buf][(512 + tid) * 8]);
    if constexpr (FUSE) {
      if (nt_ == 0) {
        // Convert-on-the-fly: fp32 -> bf16, into LDS and into xbf workspace.
        float4 v0 = *(const float4*)(af + k0);
        float4 v1 = *(const float4*)(af + k0 + 4);
        u16x8 o;
        o[0] = f2bf(v0.x); o[1] = f2bf(v0.y); o[2] = f2bf(v0.z); o[3] = f2bf(v0.w);
        o[4] = f2bf(v1.x); o[5] = f2bf(v1.y); o[6] = f2bf(v1.z); o[7] = f2bf(v1.w);
        *(u16x8*)&As[buf][tid * 8] = o;
        *(u16x8*)(axw + k0) = o;
      } else {
        GLDS16(abf + k0, &As[buf][tid * 8]);
      }
    } else {
      float4 v0 = *(const float4*)(af + k0);
      float4 v1 = *(const float4*)(af + k0 + 4);
      u16x8 o;
      o[0] = f2bf(v0.x); o[1] = f2bf(v0.y); o[2] = f2bf(v0.z); o[3] = f2bf(v0.w);
      o[4] = f2bf(v1.x); o[5] = f2bf(v1.y); o[6] = f2bf(v1.z); o[7] = f2bf(v1.w);
      *(u16x8*)&As[buf][tid * 8] = o;
    }
  };

  float racc[4][4] = {};

  // Pipeline prologue: tile (0,0) into buffer 0, drain, barrier.
  stage(0, 0, 0);
  __syncthreads();

  for (int nt = 0; nt < 4; ++nt) {
    f32x4 acc[4][4] = {};
#pragma unroll 2
    for (int kt = 0; kt < 32; ++kt) {
      const int cur = kt & 1;
      // Prefetch next tile (crosses the nt boundary to keep pipeline full).
      if (!(nt == 3 && kt == 31)) {
        int nk = kt + 1, nn = nt;
        if (nk == 32) { nk = 0; nn = nt + 1; }
        stage(cur ^ 1, nn, nk);
      }

      bf16x8 afr[4], bfr[4];
#pragma unroll
      for (int mi = 0; mi < 4; ++mi) afr[mi] = *(const bf16x8*)&As[cur][aoff[mi]];
#pragma unroll
      for (int ni = 0; ni < 4; ++ni) bfr[ni] = *(const bf16x8*)&Bs[cur][boff[ni]];
#pragma unroll
      for (int mi = 0; mi < 4; ++mi)
#pragma unroll
        for (int ni = 0; ni < 4; ++ni)
          acc[mi][ni] = __builtin_amdgcn_mfma_f32_16x16x32_bf16(
              afr[mi], bfr[ni], acc[mi][ni], 0, 0, 0);
      // One barrier per kt: drains this iter's prefetch (loads AND the
      // xbf stores in pass 0) and publishes buffer cur^1.
      __syncthreads();
    }
    FOLD_EPILOGUE(acc)
  }

  // Reduce racc over the 16 columns per lane-group -> per-row logits in LDS.
#pragma unroll
  for (int mi = 0; mi < 4; ++mi)
#pragma unroll
    for (int r = 0; r < 4; ++r)
#pragma unroll
      for (int off = 1; off < 16; off <<= 1)
        racc[mi][r] += __shfl_xor(racc[mi][r], off, 64);
  __syncthreads();
  if (tid < 128) lbuf[tid] = 0.f;
  __syncthreads();
  if (lc == 0) {
#pragma unroll
    for (int mi = 0; mi < 4; ++mi)
#pragma unroll
      for (int r = 0; r < 4; ++r)
        atomicAdd(&lbuf[wm + mi * 16 + quad * 4 + r], racc[mi][r]);
  }
  __syncthreads();

  // Softmax per 2x2 window (b2 omitted: shift-invariant).
  if (tid < 32) {
    const int j = tid;
    float l0 = lbuf[2 * j], l1 = lbuf[2 * j + 1];
    float l2 = lbuf[64 + 2 * j], l3 = lbuf[65 + 2 * j];
    float mx = fmaxf(fmaxf(l0, l1), fmaxf(l2, l3));
    float e0 = __expf(l0 - mx), e1 = __expf(l1 - mx);
    float e2 = __expf(l2 - mx), e3 = __expf(l3 - mx);
    float inv = 1.0f / (e0 + e1 + e2 + e3);
    abuf[j * 4 + 0] = e0 * inv;
    abuf[j * 4 + 1] = e1 * inv;
    abuf[j * 4 + 2] = e2 * inv;
    abuf[j * 4 + 3] = e3 * inv;
  }
  __syncthreads();

  // Weighted sum: out row b*1024 + i*32 + j (block = b*32 + i). 512 threads
  // process two windows (j, j+1) concurrently: jj = tid>>8, col = tid&255.
  const int b = blockIdx.x >> 5, ii = blockIdx.x & 31;
  const int jj = tid >> 8, t = tid & 255;
  const float* xs = xsrc + (size_t)m0 * 1024;
  float* orow = out + ((size_t)(b * 1024 + ii * 32)) * 1024;
  for (int j0 = 0; j0 < 32; j0 += 2) {
    int j = j0 + jj;
    float a0 = abuf[j * 4 + 0], a1 = abuf[j * 4 + 1];
    float a2 = abuf[j * 4 + 2], a3 = abuf[j * 4 + 3];
    const float4* p0 = (const float4*)(xs + (size_t)(2 * j) * 1024);
    const float4* p1 = (const float4*)(xs + (size_t)(2 * j + 1) * 1024);
    const float4* p2 = (const float4*)(xs + (size_t)(64 + 2 * j) * 1024);
    const float4* p3 = (const float4*)(xs + (size_t)(65 + 2 * j) * 1024);
    float4 v0 = p0[t], v1 = p1[t], v2 = p2[t], v3 = p3[t];
    float4 o;
    o.x = a0 * v0.x + a1 * v1.x + a2 * v2.x + a3 * v3.x;
    o.y = a0 * v0.y + a1 * v1.y + a2 * v2.y + a3 * v3.y;
    o.z = a0 * v0.z + a1 * v1.z + a2 * v2.z + a3 * v3.z;
    o.w = a0 * v0.w + a1 * v1.w + a2 * v2.w + a3 * v3.w;
    ((float4*)(orow + (size_t)j * 1024))[t] = o;
  }
}

// ---------------------------------------------------------------------------
extern "C" void kernel_launch(void* const* d_in, const int* in_sizes, int n_in,
                              void* d_out, int out_size, void* d_ws,
                              size_t ws_size, hipStream_t stream) {
  const float* x  = (const float*)d_in[0];  // [16, 4096, 1024]
  const float* W1 = (const float*)d_in[1];  // [1024, 1024]
  const float* b1 = (const float*)d_in[2];  // [1024]
  const float* W2 = (const float*)d_in[3];  // [1024, 1]
  float* out = (float*)d_out;               // [16, 1024, 1024]

  const size_t XBF_BYTES = 134217728ull;  // 64M bf16
  const size_t W1T_BYTES = 2097152ull;

  if (ws_size >= XBF_BYTES + W1T_BYTES) {
    ushort_t* xbf = (ushort_t*)d_ws;
    ushort_t* w1t = (ushort_t*)((char*)d_ws + XBF_BYTES);
    prep_w1<<<dim3(16, 16), 256, 0, stream>>>(W1, w1t);
    gemm_fused<true><<<512, 512, 0, stream>>>(x, xbf, w1t, b1, W2, out);
  } else {
    ushort_t* w1t = (ushort_t*)d_ws;
    prep_w1<<<dim3(16, 16), 256, 0, stream>>>(W1, w1t);
    gemm_fused<false><<<512, 512, 0, stream>>>(x, nullptr, w1t, b1, W2, out);
  }
}

// Round 5
// 592.334 us; speedup vs baseline: 1.0324x; 1.0324x over previous
//
#include <hip/hip_runtime.h>
#include <hip/hip_bf16.h>

typedef float f32x4 __attribute__((ext_vector_type(4)));
typedef __bf16 bf16x8 __attribute__((ext_vector_type(8)));
typedef unsigned short ushort_t;
typedef ushort_t u16x8 __attribute__((ext_vector_type(8)));

#define GLDS16(gp, lp)                                                        \
  __builtin_amdgcn_global_load_lds(                                           \
      (__attribute__((address_space(1))) void*)(gp),                          \
      (__attribute__((address_space(3))) void*)(lp), 16, 0, 0)

#define RAW_BARRIER() asm volatile("s_barrier" ::: "memory")
#define WAIT_VMCNT(n) asm volatile("s_waitcnt vmcnt(" #n ")" ::: "memory")

__device__ __forceinline__ ushort_t f2bf(float f) {
  unsigned u = __float_as_uint(f);
  unsigned r = u + 0x7fffu + ((u >> 16) & 1u);  // round-to-nearest-even
  return (ushort_t)(r >> 16);
}

__device__ __forceinline__ int swz(int row) {
  return (row & 3) ^ ((row >> 2) & 3);
}

// ---------------------------------------------------------------------------
// W1 [K=1024][N=1024] fp32 -> w1t [N][K] bf16 (transpose + convert)
// ---------------------------------------------------------------------------
__global__ __launch_bounds__(256) void prep_w1(const float* __restrict__ w1,
                                               ushort_t* __restrict__ w1t) {
  __shared__ ushort_t tile[64][80];
  const int k0 = blockIdx.x * 64;
  const int n0 = blockIdx.y * 64;
  const int tid = threadIdx.x;
#pragma unroll
  for (int it = 0; it < 16; ++it) {
    int idx = it * 256 + tid;
    int k = idx >> 6, n = idx & 63;
    tile[n][k] = f2bf(w1[(size_t)(k0 + k) * 1024 + n0 + n]);
  }
  __syncthreads();
#pragma unroll
  for (int it = 0; it < 2; ++it) {
    int idx = it * 256 + tid;
    int n = idx >> 3, kk = (idx & 7) * 8;
    bf16x8 v = *(const bf16x8*)&tile[n][kk];
    *(bf16x8*)&w1t[(size_t)(n0 + n) * 1024 + k0 + kk] = v;
  }
}

// ---------------------------------------------------------------------------
// x fp32 [64M] -> xbf bf16 row-major [65536][1024]. Grid-stride (2048 blocks)
// to cut per-block launch overhead vs the old 32768-block one-shot.
// ---------------------------------------------------------------------------
__global__ __launch_bounds__(256) void prep_x(const float* __restrict__ x,
                                              ushort_t* __restrict__ xbf) {
  const size_t nchunks = 8388608ull;  // 64M / 8
  const size_t stride = (size_t)gridDim.x * 256;
  for (size_t c = (size_t)blockIdx.x * 256 + threadIdx.x; c < nchunks;
       c += stride) {
    size_t i = c * 8;
    float4 a = *(const float4*)(x + i);
    float4 b = *(const float4*)(x + i + 4);
    u16x8 o;
    o[0] = f2bf(a.x); o[1] = f2bf(a.y); o[2] = f2bf(a.z); o[3] = f2bf(a.w);
    o[4] = f2bf(b.x); o[5] = f2bf(b.y); o[6] = f2bf(b.z); o[7] = f2bf(b.w);
    *(u16x8*)(xbf + i) = o;
  }
}

// ---------------------------------------------------------------------------
// Fused kernel: R2 structure (512 thr / 8 waves, 2 blocks/CU, tile 128x256,
// BK=32, wave tile 64x64) upgraded with a 3-buffer LDS ring + counted vmcnt:
// stage tile T+2 during tile T; boundary = s_waitcnt vmcnt(3) (tile T+1's 3
// loads drained, T+2's 3 stay in flight) + raw s_barrier. Never vmcnt(0) in
// steady state -> the per-kt HBM-latency stall of the 2-buffer version goes
// away. LDS 72 KB -> still 2 blocks/CU.
// ---------------------------------------------------------------------------
#define FOLD_EPILOGUE(ACC)                                                    \
  {                                                                           \
    float bv[4], wv[4];                                                       \
    _Pragma("unroll") for (int ni = 0; ni < 4; ++ni) {                        \
      int col = nt * 256 + wn + ni * 16 + lc;                                 \
      bv[ni] = b1[col];                                                       \
      wv[ni] = w2[col];                                                       \
    }                                                                         \
    _Pragma("unroll") for (int mi = 0; mi < 4; ++mi)                          \
        _Pragma("unroll") for (int r = 0; r < 4; ++r) {                       \
      float s = 0.f;                                                          \
      _Pragma("unroll") for (int ni = 0; ni < 4; ++ni) {                      \
        float h = ACC[mi][ni][r] + bv[ni];                                    \
        h = h > 0.f ? h : 0.f;                                                \
        s += h * wv[ni];                                                      \
      }                                                                       \
      racc[mi][r] += s;                                                       \
    }                                                                         \
  }

template <bool A_BF16>
__global__ __launch_bounds__(512, 4) void gemm_fused(
    const void* __restrict__ aglob, const ushort_t* __restrict__ w1t,
    const float* __restrict__ b1, const float* __restrict__ w2,
    const float* __restrict__ x, float* __restrict__ out) {
  __shared__ ushort_t As[3 * 128 * 32];  // 24 KB
  __shared__ ushort_t Bs[3 * 256 * 32];  // 48 KB
  __shared__ float lbuf[128];
  __shared__ float abuf[128];  // alpha[j*4+k]

  const int tid = threadIdx.x;
  const int wave = tid >> 6, lane = tid & 63;
  const int quad = lane >> 4, lc = lane & 15;
  const int m0 = blockIdx.x * 128;
  const int wm = (wave & 1) * 64, wn = (wave >> 1) * 64;

  // Staging geometry (R2): A tile 128x32 = 512 x 16B chunks (1/thread);
  // B tile 256x32 = 1024 chunks (2/thread). Source chunk pre-swizzled.
  const int rA = tid >> 2, cA = (tid & 3) ^ swz(tid >> 2);
  const int rB0 = tid >> 2, cB0 = (tid & 3) ^ swz(rB0);
  const int rB1 = 128 + (tid >> 2), cB1 = (tid & 3) ^ swz(rB1);

  const ushort_t* abf = nullptr;
  const float* af = nullptr;
  if constexpr (A_BF16) {
    abf = (const ushort_t*)aglob + (size_t)(m0 + rA) * 1024 + cA * 8;
  } else {
    af = (const float*)aglob + (size_t)(m0 + rA) * 1024 + cA * 8;
  }
  const ushort_t* bp0 = w1t + (size_t)rB0 * 1024 + cB0 * 8;
  const ushort_t* bp1 = w1t + (size_t)rB1 * 1024 + cB1 * 8;

  int aoff[4], boff[4];
#pragma unroll
  for (int mi = 0; mi < 4; ++mi) {
    int r = wm + mi * 16 + lc;
    aoff[mi] = r * 32 + (quad ^ swz(r)) * 8;
  }
#pragma unroll
  for (int ni = 0; ni < 4; ++ni) {
    int r = wn + ni * 16 + lc;
    boff[ni] = r * 32 + (quad ^ swz(r)) * 8;
  }

  // Stage tile T into ring buffer `buf` (3 vmcnt ops on the bf16 path).
  auto stage = [&](int buf, int T_) {
    const int nt_ = T_ >> 5, kt_ = T_ & 31;
    const size_t cb = (size_t)nt_ * (256 * 1024);
    const int k0 = kt_ * 32;
    ushort_t* Bsb = Bs + buf * 8192;
    ushort_t* Asb = As + buf * 4096;
    GLDS16(bp0 + cb + k0, Bsb + tid * 8);
    GLDS16(bp1 + cb + k0, Bsb + (512 + tid) * 8);
    if constexpr (A_BF16) {
      GLDS16(abf + k0, Asb + tid * 8);
    } else {
      float4 v0 = *(const float4*)(af + k0);
      float4 v1 = *(const float4*)(af + k0 + 4);
      u16x8 o;
      o[0] = f2bf(v0.x); o[1] = f2bf(v0.y); o[2] = f2bf(v0.z); o[3] = f2bf(v0.w);
      o[4] = f2bf(v1.x); o[5] = f2bf(v1.y); o[6] = f2bf(v1.z); o[7] = f2bf(v1.w);
      *(u16x8*)(Asb + tid * 8) = o;
    }
  };

  float racc[4][4] = {};
  f32x4 acc[4][4] = {};

  // Prologue: stage tiles 0,1 into bufs 0,1; wait tile 0 (3 newest in flight).
  stage(0, 0);
  stage(1, 1);
  if constexpr (A_BF16) { WAIT_VMCNT(3); }
  else { WAIT_VMCNT(2); asm volatile("s_waitcnt lgkmcnt(0)" ::: "memory"); }
  RAW_BARRIER();

  int bc = 0;  // current ring buffer = T % 3
#pragma unroll 1
  for (int T = 0; T < 128; ++T) {
    const int nt = T >> 5;
    int sb = bc + 2; if (sb >= 3) sb -= 3;
    if (T < 126) stage(sb, T + 2);

    const ushort_t* Asc = As + bc * 4096;
    const ushort_t* Bsc = Bs + bc * 8192;
    bf16x8 afr[4], bfr[4];
#pragma unroll
    for (int mi = 0; mi < 4; ++mi) afr[mi] = *(const bf16x8*)&Asc[aoff[mi]];
#pragma unroll
    for (int ni = 0; ni < 4; ++ni) bfr[ni] = *(const bf16x8*)&Bsc[boff[ni]];
#pragma unroll
    for (int mi = 0; mi < 4; ++mi)
#pragma unroll
      for (int ni = 0; ni < 4; ++ni)
        acc[mi][ni] = __builtin_amdgcn_mfma_f32_16x16x32_bf16(
            afr[mi], bfr[ni], acc[mi][ni], 0, 0, 0);

    if ((T & 31) == 31) {
      FOLD_EPILOGUE(acc)
#pragma unroll
      for (int mi = 0; mi < 4; ++mi)
#pragma unroll
        for (int ni = 0; ni < 4; ++ni) acc[mi][ni] = (f32x4){0.f, 0.f, 0.f, 0.f};
    }

    // Boundary: tile T+1 must be resident; keep T+2's loads in flight.
    if constexpr (A_BF16) {
      if (T < 126) { WAIT_VMCNT(3); }
      else if (T == 126) { WAIT_VMCNT(0); }
    } else {
      asm volatile("s_waitcnt vmcnt(0) lgkmcnt(0)" ::: "memory");
    }
    if (T < 127) RAW_BARRIER();
    bc = (bc == 2) ? 0 : bc + 1;
  }

  // Reduce racc over the 16 columns per lane-group -> per-row logits in LDS.
#pragma unroll
  for (int mi = 0; mi < 4; ++mi)
#pragma unroll
    for (int r = 0; r < 4; ++r)
#pragma unroll
      for (int off = 1; off < 16; off <<= 1)
        racc[mi][r] += __shfl_xor(racc[mi][r], off, 64);
  __syncthreads();
  if (tid < 128) lbuf[tid] = 0.f;
  __syncthreads();
  if (lc == 0) {
#pragma unroll
    for (int mi = 0; mi < 4; ++mi)
#pragma unroll
      for (int r = 0; r < 4; ++r)
        atomicAdd(&lbuf[wm + mi * 16 + quad * 4 + r], racc[mi][r]);
  }
  __syncthreads();

  // Softmax per 2x2 window (b2 omitted: shift-invariant).
  if (tid < 32) {
    const int j = tid;
    float l0 = lbuf[2 * j], l1 = lbuf[2 * j + 1];
    float l2 = lbuf[64 + 2 * j], l3 = lbuf[65 + 2 * j];
    float mx = fmaxf(fmaxf(l0, l1), fmaxf(l2, l3));
    float e0 = __expf(l0 - mx), e1 = __expf(l1 - mx);
    float e2 = __expf(l2 - mx), e3 = __expf(l3 - mx);
    float inv = 1.0f / (e0 + e1 + e2 + e3);
    abuf[j * 4 + 0] = e0 * inv;
    abuf[j * 4 + 1] = e1 * inv;
    abuf[j * 4 + 2] = e2 * inv;
    abuf[j * 4 + 3] = e3 * inv;
  }
  __syncthreads();

  // Weighted sum: out row b*1024 + i*32 + j (block = b*32 + i). 512 threads
  // process two windows (j, j+1) concurrently: jj = tid>>8, col = tid&255.
  const int b = blockIdx.x >> 5, ii = blockIdx.x & 31;
  const int jj = tid >> 8, t = tid & 255;
  const float* xs = x + (size_t)m0 * 1024;
  float* orow = out + ((size_t)(b * 1024 + ii * 32)) * 1024;
  for (int j0 = 0; j0 < 32; j0 += 2) {
    int j = j0 + jj;
    float a0 = abuf[j * 4 + 0], a1 = abuf[j * 4 + 1];
    float a2 = abuf[j * 4 + 2], a3 = abuf[j * 4 + 3];
    const float4* p0 = (const float4*)(xs + (size_t)(2 * j) * 1024);
    const float4* p1 = (const float4*)(xs + (size_t)(2 * j + 1) * 1024);
    const float4* p2 = (const float4*)(xs + (size_t)(64 + 2 * j) * 1024);
    const float4* p3 = (const float4*)(xs + (size_t)(65 + 2 * j) * 1024);
    float4 v0 = p0[t], v1 = p1[t], v2 = p2[t], v3 = p3[t];
    float4 o;
    o.x = a0 * v0.x + a1 * v1.x + a2 * v2.x + a3 * v3.x;
    o.y = a0 * v0.y + a1 * v1.y + a2 * v2.y + a3 * v3.y;
    o.z = a0 * v0.z + a1 * v1.z + a2 * v2.z + a3 * v3.z;
    o.w = a0 * v0.w + a1 * v1.w + a2 * v2.w + a3 * v3.w;
    ((float4*)(orow + (size_t)j * 1024))[t] = o;
  }
}

// ---------------------------------------------------------------------------
extern "C" void kernel_launch(void* const* d_in, const int* in_sizes, int n_in,
                              void* d_out, int out_size, void* d_ws,
                              size_t ws_size, hipStream_t stream) {
  const float* x  = (const float*)d_in[0];  // [16, 4096, 1024]
  const float* W1 = (const float*)d_in[1];  // [1024, 1024]
  const float* b1 = (const float*)d_in[2];  // [1024]
  const float* W2 = (const float*)d_in[3];  // [1024, 1]
  float* out = (float*)d_out;               // [16, 1024, 1024]

  const size_t XBF_BYTES = 134217728ull;  // 64M bf16
  const size_t W1T_BYTES = 2097152ull;

  if (ws_size >= XBF_BYTES + W1T_BYTES) {
    ushort_t* xbf = (ushort_t*)d_ws;
    ushort_t* w1t = (ushort_t*)((char*)d_ws + XBF_BYTES);
    prep_x<<<2048, 256, 0, stream>>>(x, xbf);
    prep_w1<<<dim3(16, 16), 256, 0, stream>>>(W1, w1t);
    gemm_fused<true><<<512, 512, 0, stream>>>(xbf, w1t, b1, W2, x, out);
  } else {
    ushort_t* w1t = (ushort_t*)d_ws;
    prep_w1<<<dim3(16, 16), 256, 0, stream>>>(W1, w1t);
    gemm_fused<false><<<512, 512, 0, stream>>>(x, w1t, b1, W2, x, out);
  }
}

// Round 6
// 587.342 us; speedup vs baseline: 1.0412x; 1.0085x over previous
//
#include <hip/hip_runtime.h>
#include <hip/hip_bf16.h>

typedef float f32x4 __attribute__((ext_vector_type(4)));
typedef __bf16 bf16x8 __attribute__((ext_vector_type(8)));
typedef unsigned short ushort_t;
typedef ushort_t u16x8 __attribute__((ext_vector_type(8)));

#define GLDS16(gp, lp)                                                        \
  __builtin_amdgcn_global_load_lds(                                           \
      (__attribute__((address_space(1))) void*)(gp),                          \
      (__attribute__((address_space(3))) void*)(lp), 16, 0, 0)

#define RAW_BARRIER() asm volatile("s_barrier" ::: "memory")
#define WAIT_VMCNT(n) asm volatile("s_waitcnt vmcnt(" #n ")" ::: "memory")

__device__ __forceinline__ ushort_t f2bf(float f) {
  unsigned u = __float_as_uint(f);
  unsigned r = u + 0x7fffu + ((u >> 16) & 1u);  // round-to-nearest-even
  return (ushort_t)(r >> 16);
}

__device__ __forceinline__ int swz(int row) {
  return (row & 3) ^ ((row >> 2) & 3);
}

// ---------------------------------------------------------------------------
// W1 [K=1024][N=1024] fp32 -> w1t [N][K] bf16 (transpose + convert)
// ---------------------------------------------------------------------------
__global__ __launch_bounds__(256) void prep_w1(const float* __restrict__ w1,
                                               ushort_t* __restrict__ w1t) {
  __shared__ ushort_t tile[64][80];
  const int k0 = blockIdx.x * 64;
  const int n0 = blockIdx.y * 64;
  const int tid = threadIdx.x;
#pragma unroll
  for (int it = 0; it < 16; ++it) {
    int idx = it * 256 + tid;
    int k = idx >> 6, n = idx & 63;
    tile[n][k] = f2bf(w1[(size_t)(k0 + k) * 1024 + n0 + n]);
  }
  __syncthreads();
#pragma unroll
  for (int it = 0; it < 2; ++it) {
    int idx = it * 256 + tid;
    int n = idx >> 3, kk = (idx & 7) * 8;
    bf16x8 v = *(const bf16x8*)&tile[n][kk];
    *(bf16x8*)&w1t[(size_t)(n0 + n) * 1024 + k0 + kk] = v;
  }
}

// ---------------------------------------------------------------------------
// Fused kernel (512 thr / 8 waves, 2 blocks/CU, tile 128x256 per nt-pass,
// BK=32, 3-buffer ring K-loop -- R5 structure, unchanged).
// NEW: prep_x is absorbed as a BLOCK-LOCAL PRE-PASS: each block converts its
// own 128x1024 fp32 strip to bf16 -> xbf (global) ONCE, syncs (vmcnt(0)
// drain makes stores visible to this CU's subsequent global_load_lds), then
// the K-loop reads xbf exactly as before. Conversion is outside the K-loop
// rhythm, so the steady state is untouched (R4's mistake avoided).
// ---------------------------------------------------------------------------
#define FOLD_EPILOGUE(ACC)                                                    \
  {                                                                           \
    float bv[4], wv[4];                                                       \
    _Pragma("unroll") for (int ni = 0; ni < 4; ++ni) {                        \
      int col = nt * 256 + wn + ni * 16 + lc;                                 \
      bv[ni] = b1[col];                                                       \
      wv[ni] = w2[col];                                                       \
    }                                                                         \
    _Pragma("unroll") for (int mi = 0; mi < 4; ++mi)                          \
        _Pragma("unroll") for (int r = 0; r < 4; ++r) {                       \
      float s = 0.f;                                                          \
      _Pragma("unroll") for (int ni = 0; ni < 4; ++ni) {                      \
        float h = ACC[mi][ni][r] + bv[ni];                                    \
        h = h > 0.f ? h : 0.f;                                                \
        s += h * wv[ni];                                                      \
      }                                                                       \
      racc[mi][r] += s;                                                       \
    }                                                                         \
  }

template <bool FUSE>
__global__ __launch_bounds__(512, 4) void gemm_fused(
    const float* __restrict__ xsrc, ushort_t* __restrict__ xbf,
    const ushort_t* __restrict__ w1t, const float* __restrict__ b1,
    const float* __restrict__ w2, float* __restrict__ out) {
  __shared__ ushort_t As[3 * 128 * 32];  // 24 KB
  __shared__ ushort_t Bs[3 * 256 * 32];  // 48 KB
  __shared__ float lbuf[128];
  __shared__ float abuf[128];  // alpha[j*4+k]

  const int tid = threadIdx.x;
  const int wave = tid >> 6, lane = tid & 63;
  const int quad = lane >> 4, lc = lane & 15;
  const int m0 = blockIdx.x * 128;
  const int wm = (wave & 1) * 64, wn = (wave >> 1) * 64;

  // -------- Pre-pass: convert this block's 128x1024 fp32 strip -> xbf -----
  if constexpr (FUSE) {
    const float* src = xsrc + (size_t)m0 * 1024;
    ushort_t* dst = xbf + (size_t)m0 * 1024;
#pragma unroll 4
    for (int it = 0; it < 32; ++it) {
      size_t i = (size_t)(it * 512 + tid) * 8;
      float4 a = *(const float4*)(src + i);
      float4 b = *(const float4*)(src + i + 4);
      u16x8 o;
      o[0] = f2bf(a.x); o[1] = f2bf(a.y); o[2] = f2bf(a.z); o[3] = f2bf(a.w);
      o[4] = f2bf(b.x); o[5] = f2bf(b.y); o[6] = f2bf(b.z); o[7] = f2bf(b.w);
      *(u16x8*)(dst + i) = o;
    }
    __syncthreads();  // vmcnt(0) drain: stores visible to our GLDS reads
  }

  // Staging geometry: A tile 128x32 = 512 x 16B chunks (1/thread);
  // B tile 256x32 = 1024 chunks (2/thread). Source chunk pre-swizzled.
  const int rA = tid >> 2, cA = (tid & 3) ^ swz(tid >> 2);
  const int rB0 = tid >> 2, cB0 = (tid & 3) ^ swz(rB0);
  const int rB1 = 128 + (tid >> 2), cB1 = (tid & 3) ^ swz(rB1);

  const ushort_t* abf = nullptr;
  const float* af = nullptr;
  if constexpr (FUSE) {
    abf = (const ushort_t*)xbf + (size_t)(m0 + rA) * 1024 + cA * 8;
  } else {
    af = xsrc + (size_t)(m0 + rA) * 1024 + cA * 8;
  }
  const ushort_t* bp0 = w1t + (size_t)rB0 * 1024 + cB0 * 8;
  const ushort_t* bp1 = w1t + (size_t)rB1 * 1024 + cB1 * 8;

  int aoff[4], boff[4];
#pragma unroll
  for (int mi = 0; mi < 4; ++mi) {
    int r = wm + mi * 16 + lc;
    aoff[mi] = r * 32 + (quad ^ swz(r)) * 8;
  }
#pragma unroll
  for (int ni = 0; ni < 4; ++ni) {
    int r = wn + ni * 16 + lc;
    boff[ni] = r * 32 + (quad ^ swz(r)) * 8;
  }

  // Stage tile T into ring buffer `buf` (3 vmcnt ops on the FUSE path).
  auto stage = [&](int buf, int T_) {
    const int nt_ = T_ >> 5, kt_ = T_ & 31;
    const size_t cb = (size_t)nt_ * (256 * 1024);
    const int k0 = kt_ * 32;
    ushort_t* Bsb = Bs + buf * 8192;
    ushort_t* Asb = As + buf * 4096;
    GLDS16(bp0 + cb + k0, Bsb + tid * 8);
    GLDS16(bp1 + cb + k0, Bsb + (512 + tid) * 8);
    if constexpr (FUSE) {
      GLDS16(abf + k0, Asb + tid * 8);
    } else {
      float4 v0 = *(const float4*)(af + k0);
      float4 v1 = *(const float4*)(af + k0 + 4);
      u16x8 o;
      o[0] = f2bf(v0.x); o[1] = f2bf(v0.y); o[2] = f2bf(v0.z); o[3] = f2bf(v0.w);
      o[4] = f2bf(v1.x); o[5] = f2bf(v1.y); o[6] = f2bf(v1.z); o[7] = f2bf(v1.w);
      *(u16x8*)(Asb + tid * 8) = o;
    }
  };

  float racc[4][4] = {};
  f32x4 acc[4][4] = {};

  // Prologue: stage tiles 0,1 into bufs 0,1; wait tile 0 (3 newest in flight).
  stage(0, 0);
  stage(1, 1);
  if constexpr (FUSE) { WAIT_VMCNT(3); }
  else { WAIT_VMCNT(2); asm volatile("s_waitcnt lgkmcnt(0)" ::: "memory"); }
  RAW_BARRIER();

  int bc = 0;  // current ring buffer = T % 3
#pragma unroll 1
  for (int T = 0; T < 128; ++T) {
    const int nt = T >> 5;
    int sb = bc + 2; if (sb >= 3) sb -= 3;
    if (T < 126) stage(sb, T + 2);

    const ushort_t* Asc = As + bc * 4096;
    const ushort_t* Bsc = Bs + bc * 8192;
    bf16x8 afr[4], bfr[4];
#pragma unroll
    for (int mi = 0; mi < 4; ++mi) afr[mi] = *(const bf16x8*)&Asc[aoff[mi]];
#pragma unroll
    for (int ni = 0; ni < 4; ++ni) bfr[ni] = *(const bf16x8*)&Bsc[boff[ni]];
#pragma unroll
    for (int mi = 0; mi < 4; ++mi)
#pragma unroll
      for (int ni = 0; ni < 4; ++ni)
        acc[mi][ni] = __builtin_amdgcn_mfma_f32_16x16x32_bf16(
            afr[mi], bfr[ni], acc[mi][ni], 0, 0, 0);

    if ((T & 31) == 31) {
      FOLD_EPILOGUE(acc)
#pragma unroll
      for (int mi = 0; mi < 4; ++mi)
#pragma unroll
        for (int ni = 0; ni < 4; ++ni) acc[mi][ni] = (f32x4){0.f, 0.f, 0.f, 0.f};
    }

    // Boundary: tile T+1 must be resident; keep T+2's loads in flight.
    if constexpr (FUSE) {
      if (T < 126) { WAIT_VMCNT(3); }
      else if (T == 126) { WAIT_VMCNT(0); }
    } else {
      asm volatile("s_waitcnt vmcnt(0) lgkmcnt(0)" ::: "memory");
    }
    if (T < 127) RAW_BARRIER();
    bc = (bc == 2) ? 0 : bc + 1;
  }

  // Reduce racc over the 16 columns per lane-group -> per-row logits in LDS.
#pragma unroll
  for (int mi = 0; mi < 4; ++mi)
#pragma unroll
    for (int r = 0; r < 4; ++r)
#pragma unroll
      for (int off = 1; off < 16; off <<= 1)
        racc[mi][r] += __shfl_xor(racc[mi][r], off, 64);
  __syncthreads();
  if (tid < 128) lbuf[tid] = 0.f;
  __syncthreads();
  if (lc == 0) {
#pragma unroll
    for (int mi = 0; mi < 4; ++mi)
#pragma unroll
      for (int r = 0; r < 4; ++r)
        atomicAdd(&lbuf[wm + mi * 16 + quad * 4 + r], racc[mi][r]);
  }
  __syncthreads();

  // Softmax per 2x2 window (b2 omitted: shift-invariant).
  if (tid < 32) {
    const int j = tid;
    float l0 = lbuf[2 * j], l1 = lbuf[2 * j + 1];
    float l2 = lbuf[64 + 2 * j], l3 = lbuf[65 + 2 * j];
    float mx = fmaxf(fmaxf(l0, l1), fmaxf(l2, l3));
    float e0 = __expf(l0 - mx), e1 = __expf(l1 - mx);
    float e2 = __expf(l2 - mx), e3 = __expf(l3 - mx);
    float inv = 1.0f / (e0 + e1 + e2 + e3);
    abuf[j * 4 + 0] = e0 * inv;
    abuf[j * 4 + 1] = e1 * inv;
    abuf[j * 4 + 2] = e2 * inv;
    abuf[j * 4 + 3] = e3 * inv;
  }
  __syncthreads();

  // Weighted sum: out row b*1024 + i*32 + j (block = b*32 + i). 512 threads
  // process two windows (j, j+1) concurrently: jj = tid>>8, col = tid&255.
  const int b = blockIdx.x >> 5, ii = blockIdx.x & 31;
  const int jj = tid >> 8, t = tid & 255;
  const float* xs = xsrc + (size_t)m0 * 1024;
  float* orow = out + ((size_t)(b * 1024 + ii * 32)) * 1024;
  for (int j0 = 0; j0 < 32; j0 += 2) {
    int j = j0 + jj;
    float a0 = abuf[j * 4 + 0], a1 = abuf[j * 4 + 1];
    float a2 = abuf[j * 4 + 2], a3 = abuf[j * 4 + 3];
    const float4* p0 = (const float4*)(xs + (size_t)(2 * j) * 1024);
    const float4* p1 = (const float4*)(xs + (size_t)(2 * j + 1) * 1024);
    const float4* p2 = (const float4*)(xs + (size_t)(64 + 2 * j) * 1024);
    const float4* p3 = (const float4*)(xs + (size_t)(65 + 2 * j) * 1024);
    float4 v0 = p0[t], v1 = p1[t], v2 = p2[t], v3 = p3[t];
    float4 o;
    o.x = a0 * v0.x + a1 * v1.x + a2 * v2.x + a3 * v3.x;
    o.y = a0 * v0.y + a1 * v1.y + a2 * v2.y + a3 * v3.y;
    o.z = a0 * v0.z + a1 * v1.z + a2 * v2.z + a3 * v3.z;
    o.w = a0 * v0.w + a1 * v1.w + a2 * v2.w + a3 * v3.w;
    ((float4*)(orow + (size_t)j * 1024))[t] = o;
  }
}

// ---------------------------------------------------------------------------
extern "C" void kernel_launch(void* const* d_in, const int* in_sizes, int n_in,
                              void* d_out, int out_size, void* d_ws,
                              size_t ws_size, hipStream_t stream) {
  const float* x  = (const float*)d_in[0];  // [16, 4096, 1024]
  const float* W1 = (const float*)d_in[1];  // [1024, 1024]
  const float* b1 = (const float*)d_in[2];  // [1024]
  const float* W2 = (const float*)d_in[3];  // [1024, 1]
  float* out = (float*)d_out;               // [16, 1024, 1024]

  const size_t XBF_BYTES = 134217728ull;  // 64M bf16
  const size_t W1T_BYTES = 2097152ull;

  if (ws_size >= XBF_BYTES + W1T_BYTES) {
    ushort_t* xbf = (ushort_t*)d_ws;
    ushort_t* w1t = (ushort_t*)((char*)d_ws + XBF_BYTES);
    prep_w1<<<dim3(16, 16), 256, 0, stream>>>(W1, w1t);
    gemm_fused<true><<<512, 512, 0, stream>>>(x, xbf, w1t, b1, W2, out);
  } else {
    ushort_t* w1t = (ushort_t*)d_ws;
    prep_w1<<<dim3(16, 16), 256, 0, stream>>>(W1, w1t);
    gemm_fused<false><<<512, 512, 0, stream>>>(x, nullptr, w1t, b1, W2, out);
  }
}